// Round 7
// baseline (354.622 us; speedup 1.0000x reference)
//
#include <hip/hip_runtime.h>
#include <hip/hip_bf16.h>

#define T_SEQ   2048
#define HIDDEN  2880
#define NQ      64
#define NKV     8
#define HD      64
#define QSIZE   4096   // NQ*HD
#define KVSIZE  512    // NKV*HD
#define QKV_N   5120   // QSIZE + 2*KVSIZE
#define WINDOW  128
#define SCALE_F 0.125f // HD^-0.5
// log2(150000)/32
#define ROPE_L2 0.53733241958f

typedef unsigned short u16;
typedef __attribute__((ext_vector_type(8))) short short8;
typedef __attribute__((ext_vector_type(4))) float f32x4;

__device__ __forceinline__ u16 f2bf(float f) {
  __hip_bfloat16 b = __float2bfloat16(f);
  u16 u; __builtin_memcpy(&u, &b, 2); return u;
}

__device__ __forceinline__ void gload16(const u16* g, u16* l) {
  __builtin_amdgcn_global_load_lds(
      (const __attribute__((address_space(1))) void*)g,
      (__attribute__((address_space(3))) void*)l, 16, 0, 0);
}

// ---------------- prep: cast X + transpose w_qkv ----------------
#define CAST_BLKS 5760            // 2048*2880/4/256
#define TQ_BX 80
#define TQ_BLKS (80 * 45)         // w_qkv: C=5120/64, R=2880/64
#define PREP_BLKS (CAST_BLKS + TQ_BLKS)

__global__ void prep_kernel(const float* __restrict__ hidden,
                            const float* __restrict__ w_qkv,
                            u16* __restrict__ Xb, u16* __restrict__ Wqt) {
  __shared__ float tile[64][65];
  const int b = blockIdx.x, tid = threadIdx.x;
  if (b < CAST_BLKS) {
    size_t i = (size_t)b * 256 + tid;
    float4 v = ((const float4*)hidden)[i];
    ushort4 o;
    o.x = f2bf(v.x); o.y = f2bf(v.y); o.z = f2bf(v.z); o.w = f2bf(v.w);
    ((ushort4*)Xb)[i] = o;
    return;
  }
  const int bb = b - CAST_BLKS;
  const int bx = bb % TQ_BX, by = bb / TQ_BX;
  const int r0 = by * 64, c0 = bx * 64;
  const int tx = tid & 15, ty = tid >> 4;      // 16 x 16, float4 per lane
#pragma unroll
  for (int i = 0; i < 4; ++i) {
    float4 v = *(const float4*)(w_qkv + (size_t)(r0 + ty + 16 * i) * QKV_N + c0 + tx * 4);
    tile[tx * 4 + 0][ty + 16 * i] = v.x;
    tile[tx * 4 + 1][ty + 16 * i] = v.y;
    tile[tx * 4 + 2][ty + 16 * i] = v.z;
    tile[tx * 4 + 3][ty + 16 * i] = v.w;
  }
  __syncthreads();
  const int rr8 = (tid & 7) * 8, cc0 = tid >> 3;   // short8 per lane
#pragma unroll
  for (int p = 0; p < 2; ++p) {
    int cc = cc0 + 32 * p;
    short8 o;
#pragma unroll
    for (int j = 0; j < 8; ++j) o[j] = (short)f2bf(tile[cc][rr8 + j]);
    *(short8*)(Wqt + (size_t)(c0 + cc) * HIDDEN + r0 + rr8) = o;
  }
}

// ---------------- bf16 MFMA GEMM, big tile + counted-vmcnt pipeline ----------------
// BM x 256 (BM = MFRAG*32), BK=64, 8 waves (2M x 4N), wave output MFRAG*16 x 64,
// acc[MFRAG][4]. 2 LDS buffers. Pipeline (T4, m218 mechanism):
//   iter t: STAGE(t+1 -> buf[(t+1)&1]);           // issue-early
//           s_waitcnt vmcnt(VL);                  // tile t landed, t+1 in flight
//           s_barrier;  compute(t);  s_barrier;   // B protects buf overwrite
// Loads get one full K-tile of MFMA (~1200 cyc) to cover HBM/L2 latency; the
// drain-to-0 only happens on the last tile. Race trace: WAR on buf[(t+1)&1]
// guarded by barrier B of iter t-1; RAW on buf[t&1] by vmcnt(VL)+barrier A;
// in-flight ds_reads drain via MFMA register-use waits before barrier B.
// VL = loads/thread/tile = MFRAG/2 (A) + 4 (B). R5's spill is addressed by
// relaxed launch bounds (no min-occupancy -> 256-reg cap) + 32-bit offsets.
// MODE 0: plain f32 store (col-clamped). MODE 1: fused-rope epilogue plus
// trailing blocks (bb >= GEMM_BLKS) transpose+cast w_o (2 tiles per block,
// fills the CUs the 160-block GEMM grid leaves idle). V written TRANSPOSED.
template <int MODE, int MFRAG>
__global__ __launch_bounds__(512)
void gemm8_kernel(const u16* __restrict__ A, const u16* __restrict__ B,
                  float* __restrict__ Cout, const int* __restrict__ positions,
                  u16* __restrict__ qb, u16* __restrict__ kb,
                  u16* __restrict__ vb, const float* __restrict__ tin,
                  u16* __restrict__ tout, int Kstride, int NKT,
                  int Bvalid, int Nout, int ldc, int NYT, int GEMM_BLKS) {
  constexpr int BM   = MFRAG * 32;           // 256 or 128
  constexpr int BUF  = (BM + 256) * 64;      // u16 per buffer
  constexpr int MQ   = MFRAG / 4;            // m-frags per quadrant
  constexpr int AGRP = MFRAG / 2;            // A gloads per thread per tile
  __shared__ __align__(16) u16 smem[2 * BUF];  // 128 KB / 96 KB
  const int tid = threadIdx.x;
  const int bb = blockIdx.x;

  if (MODE == 1 && bb >= GEMM_BLKS) {
    // transpose+cast w_o [4096][2880] f32 -> Wot [2880][4096] bf16.
    // 512 threads = two 64x64 tiles per block.
    const int half = tid >> 8, t2 = (bb - GEMM_BLKS) * 2 + half;
    const int tl = tid & 255;
    float (*tile)[65] = (float (*)[65])(smem + half * (64 * 65 * 2));
    const int bx = t2 % 45, by = t2 / 45;
    const int r0 = by * 64, c0 = bx * 64;
    const int tx = tl & 15, ty = tl >> 4;
#pragma unroll
    for (int i = 0; i < 4; ++i) {
      float4 v = *(const float4*)(tin + (size_t)(r0 + ty + 16 * i) * HIDDEN + c0 + tx * 4);
      tile[tx * 4 + 0][ty + 16 * i] = v.x;
      tile[tx * 4 + 1][ty + 16 * i] = v.y;
      tile[tx * 4 + 2][ty + 16 * i] = v.z;
      tile[tx * 4 + 3][ty + 16 * i] = v.w;
    }
    __syncthreads();
    const int rr8 = (tl & 7) * 8, cc0 = tl >> 3;
#pragma unroll
    for (int p = 0; p < 2; ++p) {
      int cc = cc0 + 32 * p;
      short8 o;
#pragma unroll
      for (int j = 0; j < 8; ++j) o[j] = (short)f2bf(tile[cc][rr8 + j]);
      *(short8*)(tout + (size_t)(c0 + cc) * QSIZE + r0 + rr8) = o;
    }
    return;
  }

  const int mx = bb / NYT, ny = bb % NYT;
  const int m0 = mx * BM, n0 = ny * 256;

  const int lane = tid & 63, wave = tid >> 6;
  const int quad = lane >> 4, l16 = lane & 15;
  const int wm = wave >> 2, wn = wave & 3;   // m-off wm*MFRAG*16, n-off wn*64

  // 32-bit staging offsets (all arrays < 2^31 elements); XOR swizzle on the
  // GLOBAL side, LDS linear (required by gload_lds).
  unsigned aofs[AGRP], alds[AGRP], bofs[4], blds[4];
#pragma unroll
  for (int g = 0; g < AGRP; ++g) {
    int c = g * 512 + tid;                   // [0, BM*8)
    int r = c >> 3;
    int lcol = ((c & 7) ^ (r & 7)) * 8;
    aofs[g] = (unsigned)((m0 + r) * Kstride + lcol);
    alds[g] = (unsigned)(c * 8);
  }
#pragma unroll
  for (int g = 0; g < 4; ++g) {
    int c = g * 512 + tid;                   // [0, 2048)
    int r = c >> 3;
    int lcol = ((c & 7) ^ (r & 7)) * 8;
    int br = n0 + r; br = br < Bvalid ? br : Bvalid - 1;
    bofs[g] = (unsigned)(br * Kstride + lcol);
    blds[g] = (unsigned)(BM * 64 + c * 8);
  }

  f32x4 acc[MFRAG][4] = {};
  const int sw0 = (quad ^ (l16 & 7)) * 8;

  // prologue: tile 0 -> buf0 (VL loads in flight)
  {
    u16* base = smem;
#pragma unroll
    for (int g = 0; g < AGRP; ++g) gload16(A + aofs[g], base + alds[g]);
#pragma unroll
    for (int g = 0; g < 4; ++g) gload16(B + bofs[g], base + blds[g]);
  }

  for (int t = 0; t < NKT; ++t) {
    if (t + 1 < NKT) {
      // issue-early: stage tile t+1 into the other buffer
      u16* base = smem + (size_t)((t + 1) & 1) * BUF;
      const unsigned kt = (unsigned)(t + 1) * 64u;
#pragma unroll
      for (int g = 0; g < AGRP; ++g) gload16(A + aofs[g] + kt, base + alds[g]);
#pragma unroll
      for (int g = 0; g < 4; ++g) gload16(B + bofs[g] + kt, base + blds[g]);
      // counted wait: tile t's VL loads done; t+1's VL may remain in flight
      if constexpr (MFRAG == 8) asm volatile("s_waitcnt vmcnt(8)" ::: "memory");
      else                      asm volatile("s_waitcnt vmcnt(6)" ::: "memory");
    } else {
      asm volatile("s_waitcnt vmcnt(0)" ::: "memory");
    }
    __builtin_amdgcn_s_barrier();            // (A) tile t visible to all waves

    const u16* bufr = smem + (size_t)(t & 1) * BUF;
    short8 bfr[4][2];
#pragma unroll
    for (int kk = 0; kk < 2; ++kk) {
      const int swo = sw0 ^ (kk * 32);
#pragma unroll
      for (int j = 0; j < 4; ++j)
        bfr[j][kk] = *(const short8*)(bufr + BM * 64 + (wn * 64 + j * 16 + l16) * 64 + swo);
    }
#pragma unroll
    for (int q = 0; q < 4; ++q) {
      short8 af[MQ][2];
#pragma unroll
      for (int kk = 0; kk < 2; ++kk) {
        const int swo = sw0 ^ (kk * 32);
#pragma unroll
        for (int im = 0; im < MQ; ++im)
          af[im][kk] = *(const short8*)(bufr + (wm * MFRAG * 16 + (q * MQ + im) * 16 + l16) * 64 + swo);
      }
      __builtin_amdgcn_s_setprio(1);
#pragma unroll
      for (int kk = 0; kk < 2; ++kk)
#pragma unroll
        for (int im = 0; im < MQ; ++im)
#pragma unroll
          for (int j = 0; j < 4; ++j)
            acc[q * MQ + im][j] =
                __builtin_amdgcn_mfma_f32_16x16x32_bf16(af[im][kk], bfr[j][kk], acc[q * MQ + im][j], 0, 0, 0);
      __builtin_amdgcn_s_setprio(0);
    }
    if (t + 1 < NKT) __builtin_amdgcn_s_barrier();  // (B) all reads of buf[t&1] done
  }

  if (MODE == 0) {
#pragma unroll
    for (int i = 0; i < MFRAG; ++i) {
      const int row = m0 + wm * MFRAG * 16 + i * 16 + quad * 4;
#pragma unroll
      for (int j = 0; j < 4; ++j) {
        const int col = n0 + wn * 64 + j * 16 + l16;
        if (col < Nout)
#pragma unroll
          for (int r = 0; r < 4; ++r)
            Cout[(size_t)(row + r) * ldc + col] = acc[i][j][r];
      }
    }
  } else {
    // 256-col tiles never straddle regions: Q/K at 4096=16*256, K/V at 4608=18*256.
    const int region = (n0 < QSIZE) ? 0 : (n0 < QSIZE + KVSIZE ? 1 : 2);
    if (region <= 1) {
      float invs[2];
#pragma unroll
      for (int j = 0; j < 2; ++j)
        invs[j] = exp2f(-(float)(j * 16 + l16) * ROPE_L2);
#pragma unroll
      for (int i = 0; i < MFRAG; ++i) {
#pragma unroll
        for (int r = 0; r < 4; ++r) {
          const int row = m0 + wm * MFRAG * 16 + i * 16 + quad * 4 + r;
          const float pos = (float)positions[row];
#pragma unroll
          for (int j = 0; j < 2; ++j) {
            float s, c;
            sincosf(pos * invs[j], &s, &c);
            const float x1 = acc[i][j][r], x2 = acc[i][j + 2][r];
            const float o1 = x1 * c - x2 * s, o2 = x2 * c + x1 * s;
            const int col = n0 + wn * 64 + j * 16 + l16;
            if (region == 0) {
              qb[(size_t)row * QSIZE + col] = f2bf(o1);
              qb[(size_t)row * QSIZE + col + 32] = f2bf(o2);
            } else {
              kb[(size_t)row * KVSIZE + col - QSIZE] = f2bf(o1);
              kb[(size_t)row * KVSIZE + col - QSIZE + 32] = f2bf(o2);
            }
          }
        }
      }
    } else {
      // V region: write TRANSPOSED vb_t[d][t]; lane packs 4 rows into one 8B store.
#pragma unroll
      for (int i = 0; i < MFRAG; ++i) {
        const int row = m0 + wm * MFRAG * 16 + i * 16 + quad * 4;
#pragma unroll
        for (int j = 0; j < 4; ++j) {
          const int col = n0 + wn * 64 + j * 16 + l16 - (QSIZE + KVSIZE);
          ushort4 pk;
          pk.x = f2bf(acc[i][j][0]);
          pk.y = f2bf(acc[i][j][1]);
          pk.z = f2bf(acc[i][j][2]);
          pk.w = f2bf(acc[i][j][3]);
          *(ushort4*)(vb + (size_t)col * T_SEQ + row) = pk;
        }
      }
    }
  }
}

// ---------------- windowed attention with sinks ----------------
// V arrives pre-transposed (vb_t[d][t]) -> stage straight into Vt with
// coalesced short8 loads; no LDS transpose, single barrier before main loop.
__global__ __launch_bounds__(256, 2)
void attn_kernel(const u16* __restrict__ qb, const u16* __restrict__ kb,
                 const u16* __restrict__ vb_t, const float* __restrict__ sinks,
                 u16* __restrict__ attnb) {
  __shared__ __align__(16) u16 Ks[160 * 72];      // 23040 B
  __shared__ __align__(16) u16 Vt[64 * 164];      // 20992 B, V^T [dim][key]
  __shared__ __align__(16) u16 Pb[4 * 16 * 164];  // 20992 B, per-wave P
  const int qt = blockIdx.x, g = blockIdx.y;
  const int q0 = qt * 32, kstart = q0 - 128;
  const int tid = threadIdx.x;
  const int lane = tid & 63, wave = tid >> 6;
  const int quad = lane >> 4, l16 = lane & 15;

  for (int s = tid; s < 1280; s += 256) {
    int r = s >> 3, c8 = (s & 7) * 8;
    int tg = kstart + r; tg = tg < 0 ? 0 : tg;
    *(short8*)(Ks + r * 72 + c8) =
        *(const short8*)(kb + (size_t)tg * KVSIZE + g * HD + c8);
  }
  {
    const int d = tid >> 2, q4 = tid & 3;
    const u16* vrow = vb_t + (size_t)(g * HD + d) * T_SEQ;
#pragma unroll
    for (int it = 0; it < 5; ++it) {
      int k0 = (q4 * 5 + it) * 8;                 // [0,160) step 8
      int cs = kstart + k0; cs = cs < 0 ? 0 : cs;
      *(short8*)(Vt + d * 164 + k0) = *(const short8*)(vrow + cs);
    }
  }
  __syncthreads();

  short8 bk[10][2];
#pragma unroll
  for (int jf = 0; jf < 10; ++jf)
#pragma unroll
    for (int kk = 0; kk < 2; ++kk)
      bk[jf][kk] = *(const short8*)(Ks + (jf * 16 + l16) * 72 + kk * 32 + quad * 8);

  const int strip = wave & 1, hb = wave >> 1;
  const int qrow0 = q0 + strip * 16;
  u16* Pw = Pb + wave * 16 * 164;
  for (int hh = 0; hh < 4; ++hh) {
    const int h = g * 8 + hb + hh * 2;
    short8 aq[2];
#pragma unroll
    for (int kk = 0; kk < 2; ++kk)
      aq[kk] = *(const short8*)(qb + (size_t)(qrow0 + l16) * QSIZE + h * HD + kk * 32 + quad * 8);
    f32x4 sc[10];
    __builtin_amdgcn_s_setprio(1);
#pragma unroll
    for (int jf = 0; jf < 10; ++jf) {
      f32x4 c = {0.f, 0.f, 0.f, 0.f};
#pragma unroll
      for (int kk = 0; kk < 2; ++kk)
        c = __builtin_amdgcn_mfma_f32_16x16x32_bf16(aq[kk], bk[jf][kk], c, 0, 0, 0);
      sc[jf] = c;
    }
    __builtin_amdgcn_s_setprio(0);

    const float sink = sinks[h];
    float pinv[4];
#pragma unroll
    for (int r = 0; r < 4; ++r) {
      const int qg = qrow0 + quad * 4 + r;
      float mx = -3.0e38f;
#pragma unroll
      for (int jf = 0; jf < 10; ++jf) {
        int kg = kstart + jf * 16 + l16;
        bool valid = (kg >= 0) && (kg <= qg) && (qg - kg < WINDOW);
        float sv = valid ? sc[jf][r] * SCALE_F : -3.0e38f;
        sc[jf][r] = sv;
        mx = fmaxf(mx, sv);
      }
#pragma unroll
      for (int d = 1; d < 16; d <<= 1) mx = fmaxf(mx, __shfl_xor(mx, d, 64));
      mx = fmaxf(mx, sink);
      float sum = 0.f;
#pragma unroll
      for (int jf = 0; jf < 10; ++jf) {
        float e = __expf(sc[jf][r] - mx);
        sc[jf][r] = e;
        sum += e;
      }
#pragma unroll
      for (int d = 1; d < 16; d <<= 1) sum += __shfl_xor(sum, d, 64);
      sum += __expf(sink - mx);
      pinv[r] = 1.0f / sum;
    }

#pragma unroll
    for (int jf = 0; jf < 10; ++jf)
#pragma unroll
      for (int r = 0; r < 4; ++r)
        Pw[(quad * 4 + r) * 164 + jf * 16 + l16] = f2bf(sc[jf][r] * pinv[r]);

    f32x4 o[4] = {};
    __builtin_amdgcn_s_setprio(1);
#pragma unroll
    for (int kk = 0; kk < 5; ++kk) {
      short8 ap = *(const short8*)(Pw + l16 * 164 + kk * 32 + quad * 8);
#pragma unroll
      for (int jf = 0; jf < 4; ++jf) {
        short8 bv = *(const short8*)(Vt + (jf * 16 + l16) * 164 + kk * 32 + quad * 8);
        o[jf] = __builtin_amdgcn_mfma_f32_16x16x32_bf16(ap, bv, o[jf], 0, 0, 0);
      }
    }
    __builtin_amdgcn_s_setprio(0);
#pragma unroll
    for (int jf = 0; jf < 4; ++jf)
#pragma unroll
      for (int r = 0; r < 4; ++r) {
        int qg = qrow0 + quad * 4 + r;
        attnb[(size_t)qg * QSIZE + h * HD + jf * 16 + l16] = f2bf(o[jf][r]);
      }
  }
}

extern "C" void kernel_launch(void* const* d_in, const int* in_sizes, int n_in,
                              void* d_out, int out_size, void* d_ws, size_t ws_size,
                              hipStream_t stream) {
  (void)in_sizes; (void)n_in; (void)out_size; (void)ws_size;
  const int*   positions = (const int*)d_in[0];
  const float* hidden    = (const float*)d_in[1];
  const float* w_qkv     = (const float*)d_in[2];
  const float* w_o       = (const float*)d_in[3];
  const float* sinks     = (const float*)d_in[4];

  char* p = (char*)d_ws;
  u16* Xb    = (u16*)p; p += (size_t)T_SEQ * HIDDEN * 2;
  u16* Wqt   = (u16*)p; p += (size_t)QKV_N * HIDDEN * 2;
  u16* Wot   = (u16*)p; p += (size_t)HIDDEN * QSIZE * 2;
  u16* qb    = (u16*)p; p += (size_t)T_SEQ * QSIZE * 2;
  u16* kb    = (u16*)p; p += (size_t)T_SEQ * KVSIZE * 2;
  u16* vbt   = (u16*)p; p += (size_t)T_SEQ * KVSIZE * 2;   // transposed [512][2048]
  u16* attnb = (u16*)p; p += (size_t)T_SEQ * QSIZE * 2;

  prep_kernel<<<PREP_BLKS, 256, 0, stream>>>(hidden, w_qkv, Xb, Wqt);
  // GEMM1: 256x256 tiles, M=2048(8) x N=5120(20) = 160 blocks (1/CU, single
  // round); blocks [160, 160+1440) transpose w_o (2 tiles each) on idle CUs.
  gemm8_kernel<1, 8><<<160 + 1440, 512, 0, stream>>>(
      Xb, Wqt, nullptr, positions, qb, kb, vbt, w_o, Wot,
      HIDDEN, 45, QKV_N, QKV_N, QKV_N, 20, 160);
  attn_kernel<<<dim3(T_SEQ / 32, NKV), 256, 0, stream>>>(qb, kb, vbt, sinks, attnb);
  // GEMM2: 128x256 tiles, M=2048(16) x N=2880(12, col-clamped) = 192 blocks.
  gemm8_kernel<0, 4><<<16 * 12, 512, 0, stream>>>(
      attnb, Wot, (float*)d_out, nullptr, nullptr, nullptr, nullptr,
      nullptr, nullptr, QSIZE, 64, HIDDEN, HIDDEN, HIDDEN, 12, 16 * 12);
}

// Round 8
// 318.020 us; speedup vs baseline: 1.1151x; 1.1151x over previous
//
#include <hip/hip_runtime.h>
#include <hip/hip_bf16.h>

#define T_SEQ   2048
#define HIDDEN  2880
#define NQ      64
#define NKV     8
#define HD      64
#define QSIZE   4096   // NQ*HD
#define KVSIZE  512    // NKV*HD
#define QKV_N   5120   // QSIZE + 2*KVSIZE
#define WINDOW  128
#define SCALE_F 0.125f // HD^-0.5
// log2(150000)/32
#define ROPE_L2 0.53733241958f

typedef unsigned short u16;
typedef __attribute__((ext_vector_type(8))) short short8;
typedef __attribute__((ext_vector_type(4))) float f32x4;

__device__ __forceinline__ u16 f2bf(float f) {
  __hip_bfloat16 b = __float2bfloat16(f);
  u16 u; __builtin_memcpy(&u, &b, 2); return u;
}

__device__ __forceinline__ void gload16(const u16* g, u16* l) {
  __builtin_amdgcn_global_load_lds(
      (const __attribute__((address_space(1))) void*)g,
      (__attribute__((address_space(3))) void*)l, 16, 0, 0);
}

// ---------------- prep: cast X + transpose w_qkv (w_o transpose is fused into GEMM1) ----------------
#define CAST_BLKS 5760            // 2048*2880/4/256
#define TQ_BX 80
#define TQ_BLKS (80 * 45)         // w_qkv: C=5120/64, R=2880/64
#define PREP_BLKS (CAST_BLKS + TQ_BLKS)

__global__ void prep_kernel(const float* __restrict__ hidden,
                            const float* __restrict__ w_qkv,
                            u16* __restrict__ Xb, u16* __restrict__ Wqt) {
  __shared__ float tile[64][65];
  const int b = blockIdx.x, tid = threadIdx.x;
  if (b < CAST_BLKS) {
    size_t i = (size_t)b * 256 + tid;
    float4 v = ((const float4*)hidden)[i];
    ushort4 o;
    o.x = f2bf(v.x); o.y = f2bf(v.y); o.z = f2bf(v.z); o.w = f2bf(v.w);
    ((ushort4*)Xb)[i] = o;
    return;
  }
  const int bb = b - CAST_BLKS;
  const int bx = bb % TQ_BX, by = bb / TQ_BX;
  const int r0 = by * 64, c0 = bx * 64;
  const int tx = tid & 15, ty = tid >> 4;      // 16 x 16, float4 per lane
#pragma unroll
  for (int i = 0; i < 4; ++i) {
    float4 v = *(const float4*)(w_qkv + (size_t)(r0 + ty + 16 * i) * QKV_N + c0 + tx * 4);
    tile[tx * 4 + 0][ty + 16 * i] = v.x;
    tile[tx * 4 + 1][ty + 16 * i] = v.y;
    tile[tx * 4 + 2][ty + 16 * i] = v.z;
    tile[tx * 4 + 3][ty + 16 * i] = v.w;
  }
  __syncthreads();
  const int rr8 = (tid & 7) * 8, cc0 = tid >> 3;   // short8 per lane
#pragma unroll
  for (int p = 0; p < 2; ++p) {
    int cc = cc0 + 32 * p;
    short8 o;
#pragma unroll
    for (int j = 0; j < 8; ++j) o[j] = (short)f2bf(tile[cc][rr8 + j]);
    *(short8*)(Wqt + (size_t)(c0 + cc) * HIDDEN + r0 + rr8) = o;
  }
}

// ---------------- bf16 MFMA GEMM, 64x128 tile, BK=64, XOR swizzle, 2-phase dbuf ----------------
// 2x2 waves of 32x64 each. Double-buffered LDS (2 x 24 KB). R4-best config:
// four structural variants (128x128, 3-deep counted vmcnt, 64x256, 256x256
// counted) all measured neutral-to-worse -- this is the m102-curve operating
// point for M=2048-class shapes; GEMM considered closed at ~96us.
// XCD-band mapping: block b -> xcd c=b%8 owns N-tiles [c*NYC,(c+1)*NYC).
// MODE 0: plain f32 store (col-clamped). MODE 1: fused-rope epilogue PLUS
// trailing heterogeneous blocks (bb >= GEMM_BLKS) that transpose+cast w_o.
// V region is written TRANSPOSED (vb_t[d][t]) so attn stages V without an
// LDS transpose.
template <int MODE>
__global__ __launch_bounds__(256)
void gemm_bt_kernel(const u16* __restrict__ A, const u16* __restrict__ B,
                    float* __restrict__ Cout, const int* __restrict__ positions,
                    u16* __restrict__ qb, u16* __restrict__ kb,
                    u16* __restrict__ vb, const float* __restrict__ tin,
                    u16* __restrict__ tout, int Kstride, int NKT,
                    int Bvalid, int Nout, int ldc, int NX, int NYC, int NY,
                    int GEMM_BLKS) {
  __shared__ __align__(16) u16 smem[2 * (64 + 128) * 64];   // 48 KB (2 bufs)
  const int tid = threadIdx.x;
  const int bb = blockIdx.x;

  if (MODE == 1 && bb >= GEMM_BLKS) {
    // transpose+cast w_o [4096][2880] f32 -> Wot [2880][4096] bf16
    float (*tile)[65] = (float (*)[65])smem;            // 16.6 KB, fits
    const int bt = bb - GEMM_BLKS;
    const int bx = bt % 45, by = bt / 45;
    const int r0 = by * 64, c0 = bx * 64;
    const int tx = tid & 15, ty = tid >> 4;
#pragma unroll
    for (int i = 0; i < 4; ++i) {
      float4 v = *(const float4*)(tin + (size_t)(r0 + ty + 16 * i) * HIDDEN + c0 + tx * 4);
      tile[tx * 4 + 0][ty + 16 * i] = v.x;
      tile[tx * 4 + 1][ty + 16 * i] = v.y;
      tile[tx * 4 + 2][ty + 16 * i] = v.z;
      tile[tx * 4 + 3][ty + 16 * i] = v.w;
    }
    __syncthreads();
    const int rr8 = (tid & 7) * 8, cc0 = tid >> 3;
#pragma unroll
    for (int p = 0; p < 2; ++p) {
      int cc = cc0 + 32 * p;
      short8 o;
#pragma unroll
      for (int j = 0; j < 8; ++j) o[j] = (short)f2bf(tile[cc][rr8 + j]);
      *(short8*)(tout + (size_t)(c0 + cc) * QSIZE + r0 + rr8) = o;
    }
    return;
  }

  const int xcd = bb & 7, bi = bb >> 3;
  const int ny = xcd * NYC + (bi % NYC);
  const int mx = bi / NYC;
  if (ny >= NY || mx >= NX) return;
  const int m0 = mx * 64, n0 = ny * 128;

  const int lane = tid & 63, wave = tid >> 6;
  const int quad = lane >> 4, l16 = lane & 15;
  const int wm = wave >> 1, wn = wave & 1;   // m-offset wm*32, n-offset wn*64

  const int NB = (64 + 128) * 64;            // u16 per buffer
  u16* As = smem;                 //  64 x 64 (8 KB)
  u16* Bs = smem + 64 * 64;       // 128 x 64 (16 KB)

  const u16* Aptr[2]; const u16* Bptr[4]; u16* Alds[2]; u16* Blds[4];
#pragma unroll
  for (int it = 0; it < 2; ++it) {
    int c = it * 256 + tid;                       // [0,512)
    int r = c >> 3;
    int lcol = ((c & 7) ^ (r & 7)) * 8;           // XOR swizzle on GLOBAL side
    Aptr[it] = A + (size_t)(m0 + r) * Kstride + lcol;
    Alds[it] = As + c * 8;
  }
#pragma unroll
  for (int it = 0; it < 4; ++it) {
    int c = it * 256 + tid;                       // [0,1024)
    int r = c >> 3;
    int lcol = ((c & 7) ^ (r & 7)) * 8;
    int br = n0 + r; br = br < Bvalid ? br : Bvalid - 1;
    Bptr[it] = B + (size_t)br * Kstride + lcol;
    Blds[it] = Bs + c * 8;
  }

  f32x4 acc[2][4] = {};
  const int sw0 = (quad ^ (l16 & 7)) * 8;

  // prologue: stage K-step 0 into buf 0
#pragma unroll
  for (int it = 0; it < 2; ++it) gload16(Aptr[it], Alds[it]);
#pragma unroll
  for (int it = 0; it < 4; ++it) gload16(Bptr[it], Blds[it]);
  asm volatile("s_waitcnt vmcnt(0)" ::: "memory");
  __syncthreads();

  int cur = 0;
  for (int t = 0; t < NKT; ++t) {
    // issue next K-step's loads into the other buffer BEFORE computing
    if (t + 1 < NKT) {
      const int bo = (cur ^ 1) * NB;
      const int ktn = (t + 1) * 64;
#pragma unroll
      for (int it = 0; it < 2; ++it) gload16(Aptr[it] + ktn, Alds[it] + bo);
#pragma unroll
      for (int it = 0; it < 4; ++it) gload16(Bptr[it] + ktn, Blds[it] + bo);
    }
    const u16* Ac = As + cur * NB;
    const u16* Bc = Bs + cur * NB;
#pragma unroll
    for (int kk = 0; kk < 2; ++kk) {
      const int swo = sw0 ^ (kk * 32);
      short8 af[2], bf[4];
#pragma unroll
      for (int i = 0; i < 2; ++i)
        af[i] = *(const short8*)(Ac + (wm * 32 + i * 16 + l16) * 64 + swo);
#pragma unroll
      for (int j = 0; j < 4; ++j)
        bf[j] = *(const short8*)(Bc + (wn * 64 + j * 16 + l16) * 64 + swo);
#pragma unroll
      for (int i = 0; i < 2; ++i)
#pragma unroll
        for (int j = 0; j < 4; ++j)
          acc[i][j] = __builtin_amdgcn_mfma_f32_16x16x32_bf16(af[i], bf[j], acc[i][j], 0, 0, 0);
    }
    if (t + 1 < NKT) {
      asm volatile("s_waitcnt vmcnt(0)" ::: "memory");
      __syncthreads();
      cur ^= 1;
    }
  }

  if (MODE == 0) {
#pragma unroll
    for (int i = 0; i < 2; ++i) {
      const int row = m0 + wm * 32 + i * 16 + quad * 4;
#pragma unroll
      for (int j = 0; j < 4; ++j) {
        const int col = n0 + wn * 64 + j * 16 + l16;
        if (col < Nout)
#pragma unroll
          for (int r = 0; r < 4; ++r)
            Cout[(size_t)(row + r) * ldc + col] = acc[i][j][r];
      }
    }
  } else {
    const int region = (n0 < QSIZE) ? 0 : (n0 < QSIZE + KVSIZE ? 1 : 2);
    if (region <= 1) {
      float invs[2];
#pragma unroll
      for (int j = 0; j < 2; ++j)
        invs[j] = exp2f(-(float)(j * 16 + l16) * ROPE_L2);
#pragma unroll
      for (int i = 0; i < 2; ++i) {
#pragma unroll
        for (int r = 0; r < 4; ++r) {
          const int row = m0 + wm * 32 + i * 16 + quad * 4 + r;
          const float pos = (float)positions[row];
#pragma unroll
          for (int j = 0; j < 2; ++j) {
            float s, c;
            sincosf(pos * invs[j], &s, &c);
            const float x1 = acc[i][j][r], x2 = acc[i][j + 2][r];
            const float o1 = x1 * c - x2 * s, o2 = x2 * c + x1 * s;
            const int col = n0 + wn * 64 + j * 16 + l16;
            if (region == 0) {
              qb[(size_t)row * QSIZE + col] = f2bf(o1);
              qb[(size_t)row * QSIZE + col + 32] = f2bf(o2);
            } else {
              kb[(size_t)row * KVSIZE + col - QSIZE] = f2bf(o1);
              kb[(size_t)row * KVSIZE + col - QSIZE + 32] = f2bf(o2);
            }
          }
        }
      }
    } else {
      // V region: write TRANSPOSED vb_t[d][t]; lane packs 4 rows into one 8B store.
#pragma unroll
      for (int i = 0; i < 2; ++i) {
        const int row = m0 + wm * 32 + i * 16 + quad * 4;
#pragma unroll
        for (int j = 0; j < 4; ++j) {
          const int col = n0 + wn * 64 + j * 16 + l16 - (QSIZE + KVSIZE);
          ushort4 pk;
          pk.x = f2bf(acc[i][j][0]);
          pk.y = f2bf(acc[i][j][1]);
          pk.z = f2bf(acc[i][j][2]);
          pk.w = f2bf(acc[i][j][3]);
          *(ushort4*)(vb + (size_t)col * T_SEQ + row) = pk;
        }
      }
    }
  }
}

// ---------------- windowed attention with sinks ----------------
// V arrives pre-transposed (vb_t[d][t]). LDS: Ks is dead after the bk
// register preload, and Pb is first touched only after the first softmax ->
// UNION them (23 KB) + one barrier between last Ks read and first Pb write.
// Total LDS 44 KB -> 3 blocks/CU (was 65 KB -> 2): +50% resident waves for
// this latency-bound kernel. Q-fragment loads for head hh+1 are issued right
// after hh's QK^T (depth-1 prefetch, consumed ~1000 cyc later -> hidden).
__global__ __launch_bounds__(256, 3)
void attn_kernel(const u16* __restrict__ qb, const u16* __restrict__ kb,
                 const u16* __restrict__ vb_t, const float* __restrict__ sinks,
                 u16* __restrict__ attnb) {
  __shared__ __align__(16) u16 KsP[160 * 72];     // 23040 B: Ks, then Pb (4*16*164=20992 B)
  __shared__ __align__(16) u16 Vt[64 * 164];      // 20992 B, V^T [dim][key]
  u16* Ks = KsP;
  u16* Pb = KsP;
  const int qt = blockIdx.x, g = blockIdx.y;
  const int q0 = qt * 32, kstart = q0 - 128;
  const int tid = threadIdx.x;
  const int lane = tid & 63, wave = tid >> 6;
  const int quad = lane >> 4, l16 = lane & 15;

  for (int s = tid; s < 1280; s += 256) {
    int r = s >> 3, c8 = (s & 7) * 8;
    int tg = kstart + r; tg = tg < 0 ? 0 : tg;
    *(short8*)(Ks + r * 72 + c8) =
        *(const short8*)(kb + (size_t)tg * KVSIZE + g * HD + c8);
  }
  {
    const int d = tid >> 2, q4 = tid & 3;
    const u16* vrow = vb_t + (size_t)(g * HD + d) * T_SEQ;
#pragma unroll
    for (int it = 0; it < 5; ++it) {
      int k0 = (q4 * 5 + it) * 8;                 // [0,160) step 8
      int cs = kstart + k0; cs = cs < 0 ? 0 : cs;
      *(short8*)(Vt + d * 164 + k0) = *(const short8*)(vrow + cs);
    }
  }
  __syncthreads();

  short8 bk[10][2];
#pragma unroll
  for (int jf = 0; jf < 10; ++jf)
#pragma unroll
    for (int kk = 0; kk < 2; ++kk)
      bk[jf][kk] = *(const short8*)(Ks + (jf * 16 + l16) * 72 + kk * 32 + quad * 8);

  // all waves done reading Ks before any wave writes Pb (aliased region)
  __syncthreads();

  const int strip = wave & 1, hb = wave >> 1;
  const int qrow0 = q0 + strip * 16;
  u16* Pw = Pb + wave * 16 * 164;
  const u16* qrow_base = qb + (size_t)(qrow0 + l16) * QSIZE;

  short8 aq[2];
#pragma unroll
  for (int kk = 0; kk < 2; ++kk)
    aq[kk] = *(const short8*)(qrow_base + (g * 8 + hb) * HD + kk * 32 + quad * 8);

  for (int hh = 0; hh < 4; ++hh) {
    const int h = g * 8 + hb + hh * 2;
    f32x4 sc[10];
    __builtin_amdgcn_s_setprio(1);
#pragma unroll
    for (int jf = 0; jf < 10; ++jf) {
      f32x4 c = {0.f, 0.f, 0.f, 0.f};
#pragma unroll
      for (int kk = 0; kk < 2; ++kk)
        c = __builtin_amdgcn_mfma_f32_16x16x32_bf16(aq[kk], bk[jf][kk], c, 0, 0, 0);
      sc[jf] = c;
    }
    __builtin_amdgcn_s_setprio(0);

    // depth-1 Q prefetch for next head (consumed after softmax+PV)
    short8 aqn[2];
    if (hh < 3) {
#pragma unroll
      for (int kk = 0; kk < 2; ++kk)
        aqn[kk] = *(const short8*)(qrow_base + (h + 2) * HD + kk * 32 + quad * 8);
    }

    const float sink = sinks[h];
    float pinv[4];
#pragma unroll
    for (int r = 0; r < 4; ++r) {
      const int qg = qrow0 + quad * 4 + r;
      float mx = -3.0e38f;
#pragma unroll
      for (int jf = 0; jf < 10; ++jf) {
        int kg = kstart + jf * 16 + l16;
        bool valid = (kg >= 0) && (kg <= qg) && (qg - kg < WINDOW);
        float sv = valid ? sc[jf][r] * SCALE_F : -3.0e38f;
        sc[jf][r] = sv;
        mx = fmaxf(mx, sv);
      }
#pragma unroll
      for (int d = 1; d < 16; d <<= 1) mx = fmaxf(mx, __shfl_xor(mx, d, 64));
      mx = fmaxf(mx, sink);
      float sum = 0.f;
#pragma unroll
      for (int jf = 0; jf < 10; ++jf) {
        float e = __expf(sc[jf][r] - mx);
        sc[jf][r] = e;
        sum += e;
      }
#pragma unroll
      for (int d = 1; d < 16; d <<= 1) sum += __shfl_xor(sum, d, 64);
      sum += __expf(sink - mx);
      pinv[r] = 1.0f / sum;
    }

#pragma unroll
    for (int jf = 0; jf < 10; ++jf)
#pragma unroll
      for (int r = 0; r < 4; ++r)
        Pw[(quad * 4 + r) * 164 + jf * 16 + l16] = f2bf(sc[jf][r] * pinv[r]);

    f32x4 o[4] = {};
    __builtin_amdgcn_s_setprio(1);
#pragma unroll
    for (int kk = 0; kk < 5; ++kk) {
      short8 ap = *(const short8*)(Pw + l16 * 164 + kk * 32 + quad * 8);
#pragma unroll
      for (int jf = 0; jf < 4; ++jf) {
        short8 bv = *(const short8*)(Vt + (jf * 16 + l16) * 164 + kk * 32 + quad * 8);
        o[jf] = __builtin_amdgcn_mfma_f32_16x16x32_bf16(ap, bv, o[jf], 0, 0, 0);
      }
    }
    __builtin_amdgcn_s_setprio(0);
#pragma unroll
    for (int jf = 0; jf < 4; ++jf)
#pragma unroll
      for (int r = 0; r < 4; ++r) {
        int qg = qrow0 + quad * 4 + r;
        attnb[(size_t)qg * QSIZE + h * HD + jf * 16 + l16] = f2bf(o[jf][r]);
      }
    aq[0] = aqn[0];
    aq[1] = aqn[1];
  }
}

extern "C" void kernel_launch(void* const* d_in, const int* in_sizes, int n_in,
                              void* d_out, int out_size, void* d_ws, size_t ws_size,
                              hipStream_t stream) {
  (void)in_sizes; (void)n_in; (void)out_size; (void)ws_size;
  const int*   positions = (const int*)d_in[0];
  const float* hidden    = (const float*)d_in[1];
  const float* w_qkv     = (const float*)d_in[2];
  const float* w_o       = (const float*)d_in[3];
  const float* sinks     = (const float*)d_in[4];

  char* p = (char*)d_ws;
  u16* Xb    = (u16*)p; p += (size_t)T_SEQ * HIDDEN * 2;
  u16* Wqt   = (u16*)p; p += (size_t)QKV_N * HIDDEN * 2;
  u16* Wot   = (u16*)p; p += (size_t)HIDDEN * QSIZE * 2;
  u16* qb    = (u16*)p; p += (size_t)T_SEQ * QSIZE * 2;
  u16* kb    = (u16*)p; p += (size_t)T_SEQ * KVSIZE * 2;
  u16* vbt   = (u16*)p; p += (size_t)T_SEQ * KVSIZE * 2;   // transposed [512][2048]
  u16* attnb = (u16*)p; p += (size_t)T_SEQ * QSIZE * 2;

  prep_kernel<<<PREP_BLKS, 256, 0, stream>>>(hidden, w_qkv, Xb, Wqt);
  // GEMM1: M=2048(NX=32, 64-row tiles), N=5120(NY=40,NYC=5), K=2880(NKT=45)
  // blocks [0,1280) = GEMM; [1280, 1280+2880) = fused w_o transpose
  gemm_bt_kernel<1><<<32 * 8 * 5 + 45 * 64, 256, 0, stream>>>(
      Xb, Wqt, nullptr, positions, qb, kb, vbt, w_o, Wot,
      HIDDEN, 45, QKV_N, QKV_N, QKV_N, 32, 5, 40, 32 * 8 * 5);
  attn_kernel<<<dim3(T_SEQ / 32, NKV), 256, 0, stream>>>(qb, kb, vbt, sinks, attnb);
  // GEMM2: M=2048(NX=32), N=2880(NY=23,NYC=3), K=4096(NKT=64)
  gemm_bt_kernel<0><<<32 * 8 * 3, 256, 0, stream>>>(
      attnb, Wot, (float*)d_out, nullptr, nullptr, nullptr, nullptr,
      nullptr, nullptr, QSIZE, 64, HIDDEN, HIDDEN, HIDDEN, 32, 3, 23, 32 * 8 * 3);
}

// Round 9
// 317.499 us; speedup vs baseline: 1.1169x; 1.0016x over previous
//
#include <hip/hip_runtime.h>
#include <hip/hip_bf16.h>

#define T_SEQ   2048
#define HIDDEN  2880
#define NQ      64
#define NKV     8
#define HD      64
#define QSIZE   4096   // NQ*HD
#define KVSIZE  512    // NKV*HD
#define QKV_N   5120   // QSIZE + 2*KVSIZE
#define WINDOW  128
#define SCALE_F 0.125f // HD^-0.5
// log2(150000)/32
#define ROPE_L2 0.53733241958f

typedef unsigned short u16;
typedef __attribute__((ext_vector_type(8))) short short8;
typedef __attribute__((ext_vector_type(4))) float f32x4;

__device__ __forceinline__ u16 f2bf(float f) {
  __hip_bfloat16 b = __float2bfloat16(f);
  u16 u; __builtin_memcpy(&u, &b, 2); return u;
}

__device__ __forceinline__ void gload16(const u16* g, u16* l) {
  __builtin_amdgcn_global_load_lds(
      (const __attribute__((address_space(1))) void*)g,
      (__attribute__((address_space(3))) void*)l, 16, 0, 0);
}

// ---------------- prep: cast X + transpose w_qkv (w_o transpose is fused into GEMM1) ----------------
#define CAST_BLKS 5760            // 2048*2880/4/256
#define TQ_BX 80
#define TQ_BLKS (80 * 45)         // w_qkv: C=5120/64, R=2880/64
#define PREP_BLKS (CAST_BLKS + TQ_BLKS)

__global__ void prep_kernel(const float* __restrict__ hidden,
                            const float* __restrict__ w_qkv,
                            u16* __restrict__ Xb, u16* __restrict__ Wqt) {
  __shared__ float tile[64][65];
  const int b = blockIdx.x, tid = threadIdx.x;
  if (b < CAST_BLKS) {
    size_t i = (size_t)b * 256 + tid;
    float4 v = ((const float4*)hidden)[i];
    ushort4 o;
    o.x = f2bf(v.x); o.y = f2bf(v.y); o.z = f2bf(v.z); o.w = f2bf(v.w);
    ((ushort4*)Xb)[i] = o;
    return;
  }
  const int bb = b - CAST_BLKS;
  const int bx = bb % TQ_BX, by = bb / TQ_BX;
  const int r0 = by * 64, c0 = bx * 64;
  const int tx = tid & 15, ty = tid >> 4;      // 16 x 16, float4 per lane
#pragma unroll
  for (int i = 0; i < 4; ++i) {
    float4 v = *(const float4*)(w_qkv + (size_t)(r0 + ty + 16 * i) * QKV_N + c0 + tx * 4);
    tile[tx * 4 + 0][ty + 16 * i] = v.x;
    tile[tx * 4 + 1][ty + 16 * i] = v.y;
    tile[tx * 4 + 2][ty + 16 * i] = v.z;
    tile[tx * 4 + 3][ty + 16 * i] = v.w;
  }
  __syncthreads();
  const int rr8 = (tid & 7) * 8, cc0 = tid >> 3;   // short8 per lane
#pragma unroll
  for (int p = 0; p < 2; ++p) {
    int cc = cc0 + 32 * p;
    short8 o;
#pragma unroll
    for (int j = 0; j < 8; ++j) o[j] = (short)f2bf(tile[cc][rr8 + j]);
    *(short8*)(Wqt + (size_t)(c0 + cc) * HIDDEN + r0 + rr8) = o;
  }
}

// ---------------- bf16 MFMA GEMM, 64x128 tile, BK=64, XOR swizzle, 2-phase dbuf ----------------
// 2x2 waves of 32x64 each. Double-buffered LDS (2 x 24 KB). R4-best config:
// five structural variants (128x128, 3-deep counted vmcnt, 64x256, 256x256
// coarse + counted) all measured neutral-to-worse. GEMM closed at ~96us.
// XCD-band mapping: block b -> xcd c=b%8 owns N-tiles [c*NYC,(c+1)*NYC).
// MODE 0: plain f32 store (col-clamped). MODE 1: fused-rope epilogue PLUS
// trailing heterogeneous blocks (bb >= GEMM_BLKS) that transpose+cast w_o.
// V region is written TRANSPOSED (vb_t[d][t]) so attn stages V without an
// LDS transpose.
template <int MODE>
__global__ __launch_bounds__(256)
void gemm_bt_kernel(const u16* __restrict__ A, const u16* __restrict__ B,
                    float* __restrict__ Cout, const int* __restrict__ positions,
                    u16* __restrict__ qb, u16* __restrict__ kb,
                    u16* __restrict__ vb, const float* __restrict__ tin,
                    u16* __restrict__ tout, int Kstride, int NKT,
                    int Bvalid, int Nout, int ldc, int NX, int NYC, int NY,
                    int GEMM_BLKS) {
  __shared__ __align__(16) u16 smem[2 * (64 + 128) * 64];   // 48 KB (2 bufs)
  const int tid = threadIdx.x;
  const int bb = blockIdx.x;

  if (MODE == 1 && bb >= GEMM_BLKS) {
    // transpose+cast w_o [4096][2880] f32 -> Wot [2880][4096] bf16
    float (*tile)[65] = (float (*)[65])smem;            // 16.6 KB, fits
    const int bt = bb - GEMM_BLKS;
    const int bx = bt % 45, by = bt / 45;
    const int r0 = by * 64, c0 = bx * 64;
    const int tx = tid & 15, ty = tid >> 4;
#pragma unroll
    for (int i = 0; i < 4; ++i) {
      float4 v = *(const float4*)(tin + (size_t)(r0 + ty + 16 * i) * HIDDEN + c0 + tx * 4);
      tile[tx * 4 + 0][ty + 16 * i] = v.x;
      tile[tx * 4 + 1][ty + 16 * i] = v.y;
      tile[tx * 4 + 2][ty + 16 * i] = v.z;
      tile[tx * 4 + 3][ty + 16 * i] = v.w;
    }
    __syncthreads();
    const int rr8 = (tid & 7) * 8, cc0 = tid >> 3;
#pragma unroll
    for (int p = 0; p < 2; ++p) {
      int cc = cc0 + 32 * p;
      short8 o;
#pragma unroll
      for (int j = 0; j < 8; ++j) o[j] = (short)f2bf(tile[cc][rr8 + j]);
      *(short8*)(tout + (size_t)(c0 + cc) * QSIZE + r0 + rr8) = o;
    }
    return;
  }

  const int xcd = bb & 7, bi = bb >> 3;
  const int ny = xcd * NYC + (bi % NYC);
  const int mx = bi / NYC;
  if (ny >= NY || mx >= NX) return;
  const int m0 = mx * 64, n0 = ny * 128;

  const int lane = tid & 63, wave = tid >> 6;
  const int quad = lane >> 4, l16 = lane & 15;
  const int wm = wave >> 1, wn = wave & 1;   // m-offset wm*32, n-offset wn*64

  const int NB = (64 + 128) * 64;            // u16 per buffer
  u16* As = smem;                 //  64 x 64 (8 KB)
  u16* Bs = smem + 64 * 64;       // 128 x 64 (16 KB)

  const u16* Aptr[2]; const u16* Bptr[4]; u16* Alds[2]; u16* Blds[4];
#pragma unroll
  for (int it = 0; it < 2; ++it) {
    int c = it * 256 + tid;                       // [0,512)
    int r = c >> 3;
    int lcol = ((c & 7) ^ (r & 7)) * 8;           // XOR swizzle on GLOBAL side
    Aptr[it] = A + (size_t)(m0 + r) * Kstride + lcol;
    Alds[it] = As + c * 8;
  }
#pragma unroll
  for (int it = 0; it < 4; ++it) {
    int c = it * 256 + tid;                       // [0,1024)
    int r = c >> 3;
    int lcol = ((c & 7) ^ (r & 7)) * 8;
    int br = n0 + r; br = br < Bvalid ? br : Bvalid - 1;
    Bptr[it] = B + (size_t)br * Kstride + lcol;
    Blds[it] = Bs + c * 8;
  }

  f32x4 acc[2][4] = {};
  const int sw0 = (quad ^ (l16 & 7)) * 8;

  // prologue: stage K-step 0 into buf 0
#pragma unroll
  for (int it = 0; it < 2; ++it) gload16(Aptr[it], Alds[it]);
#pragma unroll
  for (int it = 0; it < 4; ++it) gload16(Bptr[it], Blds[it]);
  asm volatile("s_waitcnt vmcnt(0)" ::: "memory");
  __syncthreads();

  int cur = 0;
  for (int t = 0; t < NKT; ++t) {
    // issue next K-step's loads into the other buffer BEFORE computing
    if (t + 1 < NKT) {
      const int bo = (cur ^ 1) * NB;
      const int ktn = (t + 1) * 64;
#pragma unroll
      for (int it = 0; it < 2; ++it) gload16(Aptr[it] + ktn, Alds[it] + bo);
#pragma unroll
      for (int it = 0; it < 4; ++it) gload16(Bptr[it] + ktn, Blds[it] + bo);
    }
    const u16* Ac = As + cur * NB;
    const u16* Bc = Bs + cur * NB;
#pragma unroll
    for (int kk = 0; kk < 2; ++kk) {
      const int swo = sw0 ^ (kk * 32);
      short8 af[2], bf[4];
#pragma unroll
      for (int i = 0; i < 2; ++i)
        af[i] = *(const short8*)(Ac + (wm * 32 + i * 16 + l16) * 64 + swo);
#pragma unroll
      for (int j = 0; j < 4; ++j)
        bf[j] = *(const short8*)(Bc + (wn * 64 + j * 16 + l16) * 64 + swo);
#pragma unroll
      for (int i = 0; i < 2; ++i)
#pragma unroll
        for (int j = 0; j < 4; ++j)
          acc[i][j] = __builtin_amdgcn_mfma_f32_16x16x32_bf16(af[i], bf[j], acc[i][j], 0, 0, 0);
    }
    if (t + 1 < NKT) {
      asm volatile("s_waitcnt vmcnt(0)" ::: "memory");
      __syncthreads();
      cur ^= 1;
    }
  }

  if (MODE == 0) {
#pragma unroll
    for (int i = 0; i < 2; ++i) {
      const int row = m0 + wm * 32 + i * 16 + quad * 4;
#pragma unroll
      for (int j = 0; j < 4; ++j) {
        const int col = n0 + wn * 64 + j * 16 + l16;
        if (col < Nout)
#pragma unroll
          for (int r = 0; r < 4; ++r)
            Cout[(size_t)(row + r) * ldc + col] = acc[i][j][r];
      }
    }
  } else {
    const int region = (n0 < QSIZE) ? 0 : (n0 < QSIZE + KVSIZE ? 1 : 2);
    if (region <= 1) {
      float invs[2];
#pragma unroll
      for (int j = 0; j < 2; ++j)
        invs[j] = exp2f(-(float)(j * 16 + l16) * ROPE_L2);
#pragma unroll
      for (int i = 0; i < 2; ++i) {
#pragma unroll
        for (int r = 0; r < 4; ++r) {
          const int row = m0 + wm * 32 + i * 16 + quad * 4 + r;
          const float pos = (float)positions[row];
#pragma unroll
          for (int j = 0; j < 2; ++j) {
            float s, c;
            sincosf(pos * invs[j], &s, &c);
            const float x1 = acc[i][j][r], x2 = acc[i][j + 2][r];
            const float o1 = x1 * c - x2 * s, o2 = x2 * c + x1 * s;
            const int col = n0 + wn * 64 + j * 16 + l16;
            if (region == 0) {
              qb[(size_t)row * QSIZE + col] = f2bf(o1);
              qb[(size_t)row * QSIZE + col + 32] = f2bf(o2);
            } else {
              kb[(size_t)row * KVSIZE + col - QSIZE] = f2bf(o1);
              kb[(size_t)row * KVSIZE + col - QSIZE + 32] = f2bf(o2);
            }
          }
        }
      }
    } else {
      // V region: write TRANSPOSED vb_t[d][t]; lane packs 4 rows into one 8B store.
#pragma unroll
      for (int i = 0; i < 2; ++i) {
        const int row = m0 + wm * 32 + i * 16 + quad * 4;
#pragma unroll
        for (int j = 0; j < 4; ++j) {
          const int col = n0 + wn * 64 + j * 16 + l16 - (QSIZE + KVSIZE);
          ushort4 pk;
          pk.x = f2bf(acc[i][j][0]);
          pk.y = f2bf(acc[i][j][1]);
          pk.z = f2bf(acc[i][j][2]);
          pk.w = f2bf(acc[i][j][3]);
          *(ushort4*)(vb + (size_t)col * T_SEQ + row) = pk;
        }
      }
    }
  }
}

// ---------------- windowed attention with sinks ----------------
// V arrives pre-transposed (vb_t[d][t]) -> stage straight into Vt with
// coalesced short8 loads; no LDS transpose, single barrier before main loop.
// R4 layout/bounds kept exactly ((256,2): 256-reg cap, no spill); single
// added change: depth-1 Q prefetch -- head hh+1's Q fragments are issued
// right after hh's QK^T and consumed ~1000 cyc later (after softmax+PV).
__global__ __launch_bounds__(256, 2)
void attn_kernel(const u16* __restrict__ qb, const u16* __restrict__ kb,
                 const u16* __restrict__ vb_t, const float* __restrict__ sinks,
                 u16* __restrict__ attnb) {
  __shared__ __align__(16) u16 Ks[160 * 72];      // 23040 B
  __shared__ __align__(16) u16 Vt[64 * 164];      // 20992 B, V^T [dim][key]
  __shared__ __align__(16) u16 Pb[4 * 16 * 164];  // 20992 B, per-wave P
  const int qt = blockIdx.x, g = blockIdx.y;
  const int q0 = qt * 32, kstart = q0 - 128;
  const int tid = threadIdx.x;
  const int lane = tid & 63, wave = tid >> 6;
  const int quad = lane >> 4, l16 = lane & 15;

  for (int s = tid; s < 1280; s += 256) {
    int r = s >> 3, c8 = (s & 7) * 8;
    int tg = kstart + r; tg = tg < 0 ? 0 : tg;
    *(short8*)(Ks + r * 72 + c8) =
        *(const short8*)(kb + (size_t)tg * KVSIZE + g * HD + c8);
  }
  {
    const int d = tid >> 2, q4 = tid & 3;
    const u16* vrow = vb_t + (size_t)(g * HD + d) * T_SEQ;
#pragma unroll
    for (int it = 0; it < 5; ++it) {
      int k0 = (q4 * 5 + it) * 8;                 // [0,160) step 8
      int cs = kstart + k0; cs = cs < 0 ? 0 : cs;
      *(short8*)(Vt + d * 164 + k0) = *(const short8*)(vrow + cs);
    }
  }
  __syncthreads();

  short8 bk[10][2];
#pragma unroll
  for (int jf = 0; jf < 10; ++jf)
#pragma unroll
    for (int kk = 0; kk < 2; ++kk)
      bk[jf][kk] = *(const short8*)(Ks + (jf * 16 + l16) * 72 + kk * 32 + quad * 8);

  const int strip = wave & 1, hb = wave >> 1;
  const int qrow0 = q0 + strip * 16;
  u16* Pw = Pb + wave * 16 * 164;
  const u16* qrow_base = qb + (size_t)(qrow0 + l16) * QSIZE;

  short8 aq[2];
#pragma unroll
  for (int kk = 0; kk < 2; ++kk)
    aq[kk] = *(const short8*)(qrow_base + (g * 8 + hb) * HD + kk * 32 + quad * 8);

  for (int hh = 0; hh < 4; ++hh) {
    const int h = g * 8 + hb + hh * 2;
    f32x4 sc[10];
    __builtin_amdgcn_s_setprio(1);
#pragma unroll
    for (int jf = 0; jf < 10; ++jf) {
      f32x4 c = {0.f, 0.f, 0.f, 0.f};
#pragma unroll
      for (int kk = 0; kk < 2; ++kk)
        c = __builtin_amdgcn_mfma_f32_16x16x32_bf16(aq[kk], bk[jf][kk], c, 0, 0, 0);
      sc[jf] = c;
    }
    __builtin_amdgcn_s_setprio(0);

    // depth-1 Q prefetch for next head (consumed after softmax+PV)
    short8 aqn[2];
    if (hh < 3) {
#pragma unroll
      for (int kk = 0; kk < 2; ++kk)
        aqn[kk] = *(const short8*)(qrow_base + (h + 2) * HD + kk * 32 + quad * 8);
    }

    const float sink = sinks[h];
    float pinv[4];
#pragma unroll
    for (int r = 0; r < 4; ++r) {
      const int qg = qrow0 + quad * 4 + r;
      float mx = -3.0e38f;
#pragma unroll
      for (int jf = 0; jf < 10; ++jf) {
        int kg = kstart + jf * 16 + l16;
        bool valid = (kg >= 0) && (kg <= qg) && (qg - kg < WINDOW);
        float sv = valid ? sc[jf][r] * SCALE_F : -3.0e38f;
        sc[jf][r] = sv;
        mx = fmaxf(mx, sv);
      }
#pragma unroll
      for (int d = 1; d < 16; d <<= 1) mx = fmaxf(mx, __shfl_xor(mx, d, 64));
      mx = fmaxf(mx, sink);
      float sum = 0.f;
#pragma unroll
      for (int jf = 0; jf < 10; ++jf) {
        float e = __expf(sc[jf][r] - mx);
        sc[jf][r] = e;
        sum += e;
      }
#pragma unroll
      for (int d = 1; d < 16; d <<= 1) sum += __shfl_xor(sum, d, 64);
      sum += __expf(sink - mx);
      pinv[r] = 1.0f / sum;
    }

#pragma unroll
    for (int jf = 0; jf < 10; ++jf)
#pragma unroll
      for (int r = 0; r < 4; ++r)
        Pw[(quad * 4 + r) * 164 + jf * 16 + l16] = f2bf(sc[jf][r] * pinv[r]);

    f32x4 o[4] = {};
    __builtin_amdgcn_s_setprio(1);
#pragma unroll
    for (int kk = 0; kk < 5; ++kk) {
      short8 ap = *(const short8*)(Pw + l16 * 164 + kk * 32 + quad * 8);
#pragma unroll
      for (int jf = 0; jf < 4; ++jf) {
        short8 bv = *(const short8*)(Vt + (jf * 16 + l16) * 164 + kk * 32 + quad * 8);
        o[jf] = __builtin_amdgcn_mfma_f32_16x16x32_bf16(ap, bv, o[jf], 0, 0, 0);
      }
    }
    __builtin_amdgcn_s_setprio(0);
#pragma unroll
    for (int jf = 0; jf < 4; ++jf)
#pragma unroll
      for (int r = 0; r < 4; ++r) {
        int qg = qrow0 + quad * 4 + r;
        attnb[(size_t)qg * QSIZE + h * HD + jf * 16 + l16] = f2bf(o[jf][r]);
      }
    aq[0] = aqn[0];
    aq[1] = aqn[1];
  }
}

extern "C" void kernel_launch(void* const* d_in, const int* in_sizes, int n_in,
                              void* d_out, int out_size, void* d_ws, size_t ws_size,
                              hipStream_t stream) {
  (void)in_sizes; (void)n_in; (void)out_size; (void)ws_size;
  const int*   positions = (const int*)d_in[0];
  const float* hidden    = (const float*)d_in[1];
  const float* w_qkv     = (const float*)d_in[2];
  const float* w_o       = (const float*)d_in[3];
  const float* sinks     = (const float*)d_in[4];

  char* p = (char*)d_ws;
  u16* Xb    = (u16*)p; p += (size_t)T_SEQ * HIDDEN * 2;
  u16* Wqt   = (u16*)p; p += (size_t)QKV_N * HIDDEN * 2;
  u16* Wot   = (u16*)p; p += (size_t)HIDDEN * QSIZE * 2;
  u16* qb    = (u16*)p; p += (size_t)T_SEQ * QSIZE * 2;
  u16* kb    = (u16*)p; p += (size_t)T_SEQ * KVSIZE * 2;
  u16* vbt   = (u16*)p; p += (size_t)T_SEQ * KVSIZE * 2;   // transposed [512][2048]
  u16* attnb = (u16*)p; p += (size_t)T_SEQ * QSIZE * 2;

  prep_kernel<<<PREP_BLKS, 256, 0, stream>>>(hidden, w_qkv, Xb, Wqt);
  // GEMM1: M=2048(NX=32, 64-row tiles), N=5120(NY=40,NYC=5), K=2880(NKT=45)
  // blocks [0,1280) = GEMM; [1280, 1280+2880) = fused w_o transpose
  gemm_bt_kernel<1><<<32 * 8 * 5 + 45 * 64, 256, 0, stream>>>(
      Xb, Wqt, nullptr, positions, qb, kb, vbt, w_o, Wot,
      HIDDEN, 45, QKV_N, QKV_N, QKV_N, 32, 5, 40, 32 * 8 * 5);
  attn_kernel<<<dim3(T_SEQ / 32, NKV), 256, 0, stream>>>(qb, kb, vbt, sinks, attnb);
  // GEMM2: M=2048(NX=32), N=2880(NY=23,NYC=3), K=4096(NKT=64)
  gemm_bt_kernel<0><<<32 * 8 * 3, 256, 0, stream>>>(
      attnb, Wot, (float*)d_out, nullptr, nullptr, nullptr, nullptr,
      nullptr, nullptr, QSIZE, 64, HIDDEN, HIDDEN, HIDDEN, 32, 3, 23, 32 * 8 * 3);
}

// Round 10
// 310.095 us; speedup vs baseline: 1.1436x; 1.0239x over previous
//
#include <hip/hip_runtime.h>
#include <hip/hip_bf16.h>

#define T_SEQ   2048
#define HIDDEN  2880
#define NQ      64
#define NKV     8
#define HD      64
#define QSIZE   4096   // NQ*HD
#define KVSIZE  512    // NKV*HD
#define QKV_N   5120   // QSIZE + 2*KVSIZE
#define WINDOW  128
#define SCALE_F 0.125f // HD^-0.5
// log2(150000)/32
#define ROPE_L2 0.53733241958f

typedef unsigned short u16;
typedef __attribute__((ext_vector_type(8))) short short8;
typedef __attribute__((ext_vector_type(4))) float f32x4;

__device__ __forceinline__ u16 f2bf(float f) {
  __hip_bfloat16 b = __float2bfloat16(f);
  u16 u; __builtin_memcpy(&u, &b, 2); return u;
}

__device__ __forceinline__ void gload16(const u16* g, u16* l) {
  __builtin_amdgcn_global_load_lds(
      (const __attribute__((address_space(1))) void*)g,
      (__attribute__((address_space(3))) void*)l, 16, 0, 0);
}

// ---------------- prep: cast X + transpose w_qkv (w_o transpose is fused into GEMM1) ----------------
#define CAST_BLKS 5760            // 2048*2880/4/256
#define TQ_BX 80
#define TQ_BLKS (80 * 45)         // w_qkv: C=5120/64, R=2880/64
#define PREP_BLKS (CAST_BLKS + TQ_BLKS)

__global__ void prep_kernel(const float* __restrict__ hidden,
                            const float* __restrict__ w_qkv,
                            u16* __restrict__ Xb, u16* __restrict__ Wqt) {
  __shared__ float tile[64][65];
  const int b = blockIdx.x, tid = threadIdx.x;
  if (b < CAST_BLKS) {
    size_t i = (size_t)b * 256 + tid;
    float4 v = ((const float4*)hidden)[i];
    ushort4 o;
    o.x = f2bf(v.x); o.y = f2bf(v.y); o.z = f2bf(v.z); o.w = f2bf(v.w);
    ((ushort4*)Xb)[i] = o;
    return;
  }
  const int bb = b - CAST_BLKS;
  const int bx = bb % TQ_BX, by = bb / TQ_BX;
  const int r0 = by * 64, c0 = bx * 64;
  const int tx = tid & 15, ty = tid >> 4;      // 16 x 16, float4 per lane
#pragma unroll
  for (int i = 0; i < 4; ++i) {
    float4 v = *(const float4*)(w_qkv + (size_t)(r0 + ty + 16 * i) * QKV_N + c0 + tx * 4);
    tile[tx * 4 + 0][ty + 16 * i] = v.x;
    tile[tx * 4 + 1][ty + 16 * i] = v.y;
    tile[tx * 4 + 2][ty + 16 * i] = v.z;
    tile[tx * 4 + 3][ty + 16 * i] = v.w;
  }
  __syncthreads();
  const int rr8 = (tid & 7) * 8, cc0 = tid >> 3;   // short8 per lane
#pragma unroll
  for (int p = 0; p < 2; ++p) {
    int cc = cc0 + 32 * p;
    short8 o;
#pragma unroll
    for (int j = 0; j < 8; ++j) o[j] = (short)f2bf(tile[cc][rr8 + j]);
    *(short8*)(Wqt + (size_t)(c0 + cc) * HIDDEN + r0 + rr8) = o;
  }
}

// ---------------- bf16 MFMA GEMM, 64x128 tile, BK=64, XOR swizzle, 2-phase dbuf ----------------
// 2x2 waves of 32x64 each. Double-buffered LDS (2 x 24 KB). Session-best
// operating point: six structural variants (128x128, 2-deep, 3-deep counted
// vmcnt, 64x256, 256x256 coarse + counted) all measured neutral-to-worse.
// XCD-band mapping: block b -> xcd c=b%8 owns N-tiles [c*NYC,(c+1)*NYC).
// MODE 0: plain f32 store (col-clamped). MODE 1: fused-rope epilogue PLUS
// trailing heterogeneous blocks (bb >= GEMM_BLKS) that transpose+cast w_o.
// V region is written TRANSPOSED (vb_t[d][t]) so attn stages V without an
// LDS transpose (producer-side transpose).
template <int MODE>
__global__ __launch_bounds__(256)
void gemm_bt_kernel(const u16* __restrict__ A, const u16* __restrict__ B,
                    float* __restrict__ Cout, const int* __restrict__ positions,
                    u16* __restrict__ qb, u16* __restrict__ kb,
                    u16* __restrict__ vb, const float* __restrict__ tin,
                    u16* __restrict__ tout, int Kstride, int NKT,
                    int Bvalid, int Nout, int ldc, int NX, int NYC, int NY,
                    int GEMM_BLKS) {
  __shared__ __align__(16) u16 smem[2 * (64 + 128) * 64];   // 48 KB (2 bufs)
  const int tid = threadIdx.x;
  const int bb = blockIdx.x;

  if (MODE == 1 && bb >= GEMM_BLKS) {
    // transpose+cast w_o [4096][2880] f32 -> Wot [2880][4096] bf16
    float (*tile)[65] = (float (*)[65])smem;            // 16.6 KB, fits
    const int bt = bb - GEMM_BLKS;
    const int bx = bt % 45, by = bt / 45;
    const int r0 = by * 64, c0 = bx * 64;
    const int tx = tid & 15, ty = tid >> 4;
#pragma unroll
    for (int i = 0; i < 4; ++i) {
      float4 v = *(const float4*)(tin + (size_t)(r0 + ty + 16 * i) * HIDDEN + c0 + tx * 4);
      tile[tx * 4 + 0][ty + 16 * i] = v.x;
      tile[tx * 4 + 1][ty + 16 * i] = v.y;
      tile[tx * 4 + 2][ty + 16 * i] = v.z;
      tile[tx * 4 + 3][ty + 16 * i] = v.w;
    }
    __syncthreads();
    const int rr8 = (tid & 7) * 8, cc0 = tid >> 3;
#pragma unroll
    for (int p = 0; p < 2; ++p) {
      int cc = cc0 + 32 * p;
      short8 o;
#pragma unroll
      for (int j = 0; j < 8; ++j) o[j] = (short)f2bf(tile[cc][rr8 + j]);
      *(short8*)(tout + (size_t)(c0 + cc) * QSIZE + r0 + rr8) = o;
    }
    return;
  }

  const int xcd = bb & 7, bi = bb >> 3;
  const int ny = xcd * NYC + (bi % NYC);
  const int mx = bi / NYC;
  if (ny >= NY || mx >= NX) return;
  const int m0 = mx * 64, n0 = ny * 128;

  const int lane = tid & 63, wave = tid >> 6;
  const int quad = lane >> 4, l16 = lane & 15;
  const int wm = wave >> 1, wn = wave & 1;   // m-offset wm*32, n-offset wn*64

  const int NB = (64 + 128) * 64;            // u16 per buffer
  u16* As = smem;                 //  64 x 64 (8 KB)
  u16* Bs = smem + 64 * 64;       // 128 x 64 (16 KB)

  const u16* Aptr[2]; const u16* Bptr[4]; u16* Alds[2]; u16* Blds[4];
#pragma unroll
  for (int it = 0; it < 2; ++it) {
    int c = it * 256 + tid;                       // [0,512)
    int r = c >> 3;
    int lcol = ((c & 7) ^ (r & 7)) * 8;           // XOR swizzle on GLOBAL side
    Aptr[it] = A + (size_t)(m0 + r) * Kstride + lcol;
    Alds[it] = As + c * 8;
  }
#pragma unroll
  for (int it = 0; it < 4; ++it) {
    int c = it * 256 + tid;                       // [0,1024)
    int r = c >> 3;
    int lcol = ((c & 7) ^ (r & 7)) * 8;
    int br = n0 + r; br = br < Bvalid ? br : Bvalid - 1;
    Bptr[it] = B + (size_t)br * Kstride + lcol;
    Blds[it] = Bs + c * 8;
  }

  f32x4 acc[2][4] = {};
  const int sw0 = (quad ^ (l16 & 7)) * 8;

  // prologue: stage K-step 0 into buf 0
#pragma unroll
  for (int it = 0; it < 2; ++it) gload16(Aptr[it], Alds[it]);
#pragma unroll
  for (int it = 0; it < 4; ++it) gload16(Bptr[it], Blds[it]);
  asm volatile("s_waitcnt vmcnt(0)" ::: "memory");
  __syncthreads();

  int cur = 0;
  for (int t = 0; t < NKT; ++t) {
    // issue next K-step's loads into the other buffer BEFORE computing
    if (t + 1 < NKT) {
      const int bo = (cur ^ 1) * NB;
      const int ktn = (t + 1) * 64;
#pragma unroll
      for (int it = 0; it < 2; ++it) gload16(Aptr[it] + ktn, Alds[it] + bo);
#pragma unroll
      for (int it = 0; it < 4; ++it) gload16(Bptr[it] + ktn, Blds[it] + bo);
    }
    const u16* Ac = As + cur * NB;
    const u16* Bc = Bs + cur * NB;
#pragma unroll
    for (int kk = 0; kk < 2; ++kk) {
      const int swo = sw0 ^ (kk * 32);
      short8 af[2], bf[4];
#pragma unroll
      for (int i = 0; i < 2; ++i)
        af[i] = *(const short8*)(Ac + (wm * 32 + i * 16 + l16) * 64 + swo);
#pragma unroll
      for (int j = 0; j < 4; ++j)
        bf[j] = *(const short8*)(Bc + (wn * 64 + j * 16 + l16) * 64 + swo);
#pragma unroll
      for (int i = 0; i < 2; ++i)
#pragma unroll
        for (int j = 0; j < 4; ++j)
          acc[i][j] = __builtin_amdgcn_mfma_f32_16x16x32_bf16(af[i], bf[j], acc[i][j], 0, 0, 0);
    }
    if (t + 1 < NKT) {
      asm volatile("s_waitcnt vmcnt(0)" ::: "memory");
      __syncthreads();
      cur ^= 1;
    }
  }

  if (MODE == 0) {
#pragma unroll
    for (int i = 0; i < 2; ++i) {
      const int row = m0 + wm * 32 + i * 16 + quad * 4;
#pragma unroll
      for (int j = 0; j < 4; ++j) {
        const int col = n0 + wn * 64 + j * 16 + l16;
        if (col < Nout)
#pragma unroll
          for (int r = 0; r < 4; ++r)
            Cout[(size_t)(row + r) * ldc + col] = acc[i][j][r];
      }
    }
  } else {
    const int region = (n0 < QSIZE) ? 0 : (n0 < QSIZE + KVSIZE ? 1 : 2);
    if (region <= 1) {
      float invs[2];
#pragma unroll
      for (int j = 0; j < 2; ++j)
        invs[j] = exp2f(-(float)(j * 16 + l16) * ROPE_L2);
#pragma unroll
      for (int i = 0; i < 2; ++i) {
#pragma unroll
        for (int r = 0; r < 4; ++r) {
          const int row = m0 + wm * 32 + i * 16 + quad * 4 + r;
          const float pos = (float)positions[row];
#pragma unroll
          for (int j = 0; j < 2; ++j) {
            float s, c;
            sincosf(pos * invs[j], &s, &c);
            const float x1 = acc[i][j][r], x2 = acc[i][j + 2][r];
            const float o1 = x1 * c - x2 * s, o2 = x2 * c + x1 * s;
            const int col = n0 + wn * 64 + j * 16 + l16;
            if (region == 0) {
              qb[(size_t)row * QSIZE + col] = f2bf(o1);
              qb[(size_t)row * QSIZE + col + 32] = f2bf(o2);
            } else {
              kb[(size_t)row * KVSIZE + col - QSIZE] = f2bf(o1);
              kb[(size_t)row * KVSIZE + col - QSIZE + 32] = f2bf(o2);
            }
          }
        }
      }
    } else {
      // V region: write TRANSPOSED vb_t[d][t]; lane packs its 4 rows (r)
      // into one 8B store.
#pragma unroll
      for (int i = 0; i < 2; ++i) {
        const int row = m0 + wm * 32 + i * 16 + quad * 4;
#pragma unroll
        for (int j = 0; j < 4; ++j) {
          const int col = n0 + wn * 64 + j * 16 + l16 - (QSIZE + KVSIZE);
          ushort4 pk;
          pk.x = f2bf(acc[i][j][0]);
          pk.y = f2bf(acc[i][j][1]);
          pk.z = f2bf(acc[i][j][2]);
          pk.w = f2bf(acc[i][j][3]);
          *(ushort4*)(vb + (size_t)col * T_SEQ + row) = pk;
        }
      }
    }
  }
}

// ---------------- windowed attention with sinks ----------------
// V arrives pre-transposed (vb_t[d][t]) -> stage straight into Vt with
// coalesced short8 loads; no LDS transpose, single barrier before main loop.
__global__ __launch_bounds__(256, 2)
void attn_kernel(const u16* __restrict__ qb, const u16* __restrict__ kb,
                 const u16* __restrict__ vb_t, const float* __restrict__ sinks,
                 u16* __restrict__ attnb) {
  __shared__ __align__(16) u16 Ks[160 * 72];      // 23040 B
  __shared__ __align__(16) u16 Vt[64 * 164];      // 20992 B, V^T [dim][key]
  __shared__ __align__(16) u16 Pb[4 * 16 * 164];  // 20992 B, per-wave P
  const int qt = blockIdx.x, g = blockIdx.y;
  const int q0 = qt * 32, kstart = q0 - 128;
  const int tid = threadIdx.x;
  const int lane = tid & 63, wave = tid >> 6;
  const int quad = lane >> 4, l16 = lane & 15;

  for (int s = tid; s < 1280; s += 256) {
    int r = s >> 3, c8 = (s & 7) * 8;
    int tg = kstart + r; tg = tg < 0 ? 0 : tg;
    *(short8*)(Ks + r * 72 + c8) =
        *(const short8*)(kb + (size_t)tg * KVSIZE + g * HD + c8);
  }
  {
    const int d = tid >> 2, q4 = tid & 3;
    const u16* vrow = vb_t + (size_t)(g * HD + d) * T_SEQ;
#pragma unroll
    for (int it = 0; it < 5; ++it) {
      int k0 = (q4 * 5 + it) * 8;                 // [0,160) step 8
      int cs = kstart + k0; cs = cs < 0 ? 0 : cs;
      *(short8*)(Vt + d * 164 + k0) = *(const short8*)(vrow + cs);
    }
  }
  __syncthreads();

  short8 bk[10][2];
#pragma unroll
  for (int jf = 0; jf < 10; ++jf)
#pragma unroll
    for (int kk = 0; kk < 2; ++kk)
      bk[jf][kk] = *(const short8*)(Ks + (jf * 16 + l16) * 72 + kk * 32 + quad * 8);

  const int strip = wave & 1, hb = wave >> 1;
  const int qrow0 = q0 + strip * 16;
  u16* Pw = Pb + wave * 16 * 164;
  for (int hh = 0; hh < 4; ++hh) {
    const int h = g * 8 + hb + hh * 2;
    short8 aq[2];
#pragma unroll
    for (int kk = 0; kk < 2; ++kk)
      aq[kk] = *(const short8*)(qb + (size_t)(qrow0 + l16) * QSIZE + h * HD + kk * 32 + quad * 8);
    f32x4 sc[10];
    __builtin_amdgcn_s_setprio(1);
#pragma unroll
    for (int jf = 0; jf < 10; ++jf) {
      f32x4 c = {0.f, 0.f, 0.f, 0.f};
#pragma unroll
      for (int kk = 0; kk < 2; ++kk)
        c = __builtin_amdgcn_mfma_f32_16x16x32_bf16(aq[kk], bk[jf][kk], c, 0, 0, 0);
      sc[jf] = c;
    }
    __builtin_amdgcn_s_setprio(0);

    const float sink = sinks[h];
    float pinv[4];
#pragma unroll
    for (int r = 0; r < 4; ++r) {
      const int qg = qrow0 + quad * 4 + r;
      float mx = -3.0e38f;
#pragma unroll
      for (int jf = 0; jf < 10; ++jf) {
        int kg = kstart + jf * 16 + l16;
        bool valid = (kg >= 0) && (kg <= qg) && (qg - kg < WINDOW);
        float sv = valid ? sc[jf][r] * SCALE_F : -3.0e38f;
        sc[jf][r] = sv;
        mx = fmaxf(mx, sv);
      }
#pragma unroll
      for (int d = 1; d < 16; d <<= 1) mx = fmaxf(mx, __shfl_xor(mx, d, 64));
      mx = fmaxf(mx, sink);
      float sum = 0.f;
#pragma unroll
      for (int jf = 0; jf < 10; ++jf) {
        float e = __expf(sc[jf][r] - mx);
        sc[jf][r] = e;
        sum += e;
      }
#pragma unroll
      for (int d = 1; d < 16; d <<= 1) sum += __shfl_xor(sum, d, 64);
      sum += __expf(sink - mx);
      pinv[r] = 1.0f / sum;
    }

#pragma unroll
    for (int jf = 0; jf < 10; ++jf)
#pragma unroll
      for (int r = 0; r < 4; ++r)
        Pw[(quad * 4 + r) * 164 + jf * 16 + l16] = f2bf(sc[jf][r] * pinv[r]);

    f32x4 o[4] = {};
    __builtin_amdgcn_s_setprio(1);
#pragma unroll
    for (int kk = 0; kk < 5; ++kk) {
      short8 ap = *(const short8*)(Pw + l16 * 164 + kk * 32 + quad * 8);
#pragma unroll
      for (int jf = 0; jf < 4; ++jf) {
        short8 bv = *(const short8*)(Vt + (jf * 16 + l16) * 164 + kk * 32 + quad * 8);
        o[jf] = __builtin_amdgcn_mfma_f32_16x16x32_bf16(ap, bv, o[jf], 0, 0, 0);
      }
    }
    __builtin_amdgcn_s_setprio(0);
#pragma unroll
    for (int jf = 0; jf < 4; ++jf)
#pragma unroll
      for (int r = 0; r < 4; ++r) {
        int qg = qrow0 + quad * 4 + r;
        attnb[(size_t)qg * QSIZE + h * HD + jf * 16 + l16] = f2bf(o[jf][r]);
      }
  }
}

extern "C" void kernel_launch(void* const* d_in, const int* in_sizes, int n_in,
                              void* d_out, int out_size, void* d_ws, size_t ws_size,
                              hipStream_t stream) {
  (void)in_sizes; (void)n_in; (void)out_size; (void)ws_size;
  const int*   positions = (const int*)d_in[0];
  const float* hidden    = (const float*)d_in[1];
  const float* w_qkv     = (const float*)d_in[2];
  const float* w_o       = (const float*)d_in[3];
  const float* sinks     = (const float*)d_in[4];

  char* p = (char*)d_ws;
  u16* Xb    = (u16*)p; p += (size_t)T_SEQ * HIDDEN * 2;
  u16* Wqt   = (u16*)p; p += (size_t)QKV_N * HIDDEN * 2;
  u16* Wot   = (u16*)p; p += (size_t)HIDDEN * QSIZE * 2;
  u16* qb    = (u16*)p; p += (size_t)T_SEQ * QSIZE * 2;
  u16* kb    = (u16*)p; p += (size_t)T_SEQ * KVSIZE * 2;
  u16* vbt   = (u16*)p; p += (size_t)T_SEQ * KVSIZE * 2;   // transposed [512][2048]
  u16* attnb = (u16*)p; p += (size_t)T_SEQ * QSIZE * 2;

  prep_kernel<<<PREP_BLKS, 256, 0, stream>>>(hidden, w_qkv, Xb, Wqt);
  // GEMM1: M=2048(NX=32, 64-row tiles), N=5120(NY=40,NYC=5), K=2880(NKT=45)
  // blocks [0,1280) = GEMM; [1280, 1280+2880) = fused w_o transpose
  gemm_bt_kernel<1><<<32 * 8 * 5 + 45 * 64, 256, 0, stream>>>(
      Xb, Wqt, nullptr, positions, qb, kb, vbt, w_o, Wot,
      HIDDEN, 45, QKV_N, QKV_N, QKV_N, 32, 5, 40, 32 * 8 * 5);
  attn_kernel<<<dim3(T_SEQ / 32, NKV), 256, 0, stream>>>(qb, kb, vbt, sinks, attnb);
  // GEMM2: M=2048(NX=32), N=2880(NY=23,NYC=3), K=4096(NKT=64)
  gemm_bt_kernel<0><<<32 * 8 * 3, 256, 0, stream>>>(
      attnb, Wot, (float*)d_out, nullptr, nullptr, nullptr, nullptr,
      nullptr, nullptr, QSIZE, 64, HIDDEN, HIDDEN, HIDDEN, 32, 3, 23, 32 * 8 * 3);
}